// Round 5
// baseline (304.962 us; speedup 1.0000x reference)
//
#include <hip/hip_runtime.h>

#define SS 512
#define BB 512
#define TT 64
#define NTHREADS 128
#define FSTRIDE ((size_t)BB * TT)

typedef float float2v __attribute__((ext_vector_type(2)));

// packed f32 add: 2 adds in 1 instruction (CDNA VOP3P)
__device__ __forceinline__ float2v pk_add(float2v a, float2v b) {
    float2v d;
    asm("v_pk_add_f32 %0, %1, %2" : "=v"(d) : "v"(a), "v"(b));
    return d;
}

// DPP quad_perm xor-1: [1,0,3,2] = 0xB1 (pair exchange, 1 VALU op)
__device__ __forceinline__ float dppf_x1(float x) {
    return __int_as_float(__builtin_amdgcn_mov_dpp(__float_as_int(x), 0xB1, 0xF, 0xF, true));
}
__device__ __forceinline__ int dppi_x1(int x) {
    return __builtin_amdgcn_mov_dpp(x, 0xB1, 0xF, 0xF, true);
}

// Raw barrier: drain LDS ops (cross-wave vbuf visibility) but NOT vmcnt --
// emission prefetch loads stay in flight across the barrier.
__device__ __forceinline__ void barrier_lgkm() {
    asm volatile("s_waitcnt lgkmcnt(0)\n\ts_barrier" ::: "memory");
}

// One block per batch element. 2 waves; tid -> (j = tid>>1, li = tid&1).
// Lane (j,li) covers source tags i in [32*li, 32*li+32).
__global__ __launch_bounds__(NTHREADS, 1) void viterbi_fused(
    const float* __restrict__ feats,   // (S,B,T)
    const float* __restrict__ mask,    // (B,S)
    const float* __restrict__ startt,  // (T,)
    const float* __restrict__ endt,    // (T,)
    const float* __restrict__ trans,   // (T,T)
    int* __restrict__ out)             // (B,S)
{
    __shared__ float vbuf[2][TT];
    __shared__ unsigned char hist[SS - 1][TT];
    __shared__ float redbuf[2];
    __shared__ int lenSh;

    const int b   = blockIdx.x;
    const int tid = threadIdx.x;
    const int j   = tid >> 1;
    const int li  = tid & 1;
    const int base_i = li * 32;
    const int wid = tid >> 6;

    // ---- transitions column slice as packed pairs (32 VGPRs) ----
    float2v tc2[16];
#pragma unroll
    for (int q = 0; q < 16; ++q) {
        float2v t;
        t.x = trans[(base_i + 2 * q) * TT + j];
        t.y = trans[(base_i + 2 * q + 1) * TT + j];
        tc2[q] = t;
    }

    // ---- init: score0 = start + feats[0] ----
    if (tid < TT) vbuf[0][tid] = startt[tid] + feats[(size_t)b * TT + tid];

    // ---- sequence length: sum of mask row (0/1 adds, exact any order) ----
    float msum = mask[b * SS + tid] + mask[b * SS + 128 + tid]
               + mask[b * SS + 256 + tid] + mask[b * SS + 384 + tid];
#pragma unroll
    for (int off = 1; off < 64; off <<= 1) msum += __shfl_xor(msum, off);
    if ((tid & 63) == 0) redbuf[wid] = msum;
    __syncthreads();
    if (tid == 0) lenSh = (int)(redbuf[0] + redbuf[1] + 0.5f);
    __syncthreads();

    const int len = lenSh;
    int p = 0;

    const float* fb = feats + (size_t)b * TT + j;   // per-thread emis pointer

    // step body: packed score adds, max3-tree max, find-first-eq index,
    // one DPP pair combine, vbuf/hist update, raw lgkm barrier.
    auto body = [&](float e, int s) {
        // v slice [base_i, base_i+32) as 8 x b128 (broadcast reads, no conflict)
        float2v vv[16];
#pragma unroll
        for (int q = 0; q < 8; ++q) {
            float4 t4 = *(const float4*)&vbuf[p][base_i + q * 4];
            float2v a; a.x = t4.x; a.y = t4.y; vv[2 * q]     = a;
            float2v c; c.x = t4.z; c.y = t4.w; vv[2 * q + 1] = c;
        }
        float2v ee; ee.x = e; ee.y = e;

        // scores, exact reference association: (v + trans) + emis
        float sc[32];
#pragma unroll
        for (int q = 0; q < 16; ++q) {
            float2v r = pk_add(pk_add(vv[q], tc2[q]), ee);
            sc[2 * q]     = r.x;
            sc[2 * q + 1] = r.y;
        }

        // exact max via fmax tree (fp max is rounding-free; v_max3 fusable)
        float t[11];
#pragma unroll
        for (int k = 0; k < 10; ++k)
            t[k] = fmaxf(fmaxf(sc[3 * k], sc[3 * k + 1]), sc[3 * k + 2]);
        t[10] = fmaxf(sc[30], sc[31]);
        float u0 = fmaxf(fmaxf(t[0], t[1]), t[2]);
        float u1 = fmaxf(fmaxf(t[3], t[4]), t[5]);
        float u2 = fmaxf(fmaxf(t[6], t[7]), t[8]);
        float u3 = fmaxf(t[9], t[10]);
        float best = fmaxf(fmaxf(fmaxf(u0, u1), u2), u3);

        // pair-combine max (both lanes of the pair see the global max)
        best = fmaxf(best, dppf_x1(best));

        // first-occurrence index: smallest k with sc[k]==best (exact eq).
        // 4 independent descending chains + min merges == first-max scan.
        int ci = 9999;
#pragma unroll
        for (int c = 0; c < 4; ++c) {
            int cc = 9999;
#pragma unroll
            for (int k = 7; k >= 0; --k) {
                int kk = c * 8 + k;
                if (sc[kk] == best) cc = kk;
            }
            ci = min(ci, cc);
        }
        int gi = base_i + ci;           // lanes with no local eq stay big
        gi = min(gi, dppi_x1(gi));      // first index across the pair

        if (li == 0) {
            vbuf[p ^ 1][j] = best;               // mask==1 here: new_v = best
            hist[s - 1][j] = (unsigned char)gi;
        }
        barrier_lgkm();
        p ^= 1;
    };

    // ---- emissions: chunked prefetch, 8 steps ahead, static reg indexing ----
    float ec[8], en[8];
#pragma unroll
    for (int u = 0; u < 8; ++u) {
        int sn = 1 + u; if (sn > SS - 1) sn = SS - 1;
        ec[u] = fb[(size_t)sn * FSTRIDE];
    }

    int s = 1;
    while (s + 8 <= len) {
#pragma unroll
        for (int u = 0; u < 8; ++u) {
            int sn = s + 8 + u; if (sn > SS - 1) sn = SS - 1;
            en[u] = fb[(size_t)sn * FSTRIDE];
        }
#pragma unroll
        for (int u = 0; u < 8; ++u) body(ec[u], s + u);
#pragma unroll
        for (int u = 0; u < 8; ++u) ec[u] = en[u];
        s += 8;
    }
#pragma unroll
    for (int u = 0; u < 7; ++u) {
        if (s + u < len) body(ec[u], s + u);
    }

    // ---- final argmax + backtrace (wave 0) ----
    if (tid < TT) {
        float fv = vbuf[p][tid] + endt[tid];
        int bix = tid;
#pragma unroll
        for (int off = 1; off < 64; off <<= 1) {
            float ov = __shfl_xor(fv, off);
            int   oi = __shfl_xor(bix, off);
            if (ov > fv || (ov == fv && oi < bix)) { fv = ov; bix = oi; }
        }
        if (tid == 0) {
            int* ob = out + (size_t)b * SS;
            int cur = bix;
            ob[SS - 1] = cur;      // decode[S-1] = last_path always
            ob[len - 1] = cur;     // position len-1 = last_path
            for (int s2 = len - 2; s2 >= 0; --s2) {
                cur = hist[s2][cur];
                ob[s2] = cur;
            }
        }
    }

    // zeros for masked region s in [len, S-2]
    for (int s2 = len + tid; s2 < SS - 1; s2 += NTHREADS)
        out[(size_t)b * SS + s2] = 0;
}

extern "C" void kernel_launch(void* const* d_in, const int* in_sizes, int n_in,
                              void* d_out, int out_size, void* d_ws, size_t ws_size,
                              hipStream_t stream) {
    const float* feats  = (const float*)d_in[0];
    const float* mask   = (const float*)d_in[1];
    const float* startt = (const float*)d_in[2];
    const float* endt   = (const float*)d_in[3];
    const float* trans  = (const float*)d_in[4];
    int* out = (int*)d_out;

    viterbi_fused<<<dim3(BB), dim3(NTHREADS), 0, stream>>>(
        feats, mask, startt, endt, trans, out);
}